// Round 11
// baseline (341.577 us; speedup 1.0000x reference)
//
#include <hip/hip_runtime.h>

typedef unsigned short ushort_t;
typedef __bf16 bf16x8 __attribute__((ext_vector_type(8)));
typedef float f32x4 __attribute__((ext_vector_type(4)));

#define S_LEN 2048
#define DMODEL 2048
#define NH 16
#define HDIM 128
#define BATCH 2
#define M_ROWS (BATCH * S_LEN) // 4096

__device__ __forceinline__ ushort_t f2bf(float f) {
    union { float f; unsigned u; } v; v.f = f;
    unsigned r = (v.u + 0x7fffu + ((v.u >> 16) & 1u)) >> 16;
    return (ushort_t)r;
}
__device__ __forceinline__ float bf2f(ushort_t u) {
    union { unsigned u; float f; } v; v.u = ((unsigned)u) << 16;
    return v.f;
}

__device__ __forceinline__ void async16(const void* g, void* l) {
    __builtin_amdgcn_global_load_lds(
        (const __attribute__((address_space(1))) void*)g,
        (__attribute__((address_space(3))) void*)l, 16, 0, 0);
}

// ---------------- fp32 -> bf16 (4 elems/thread) ----------------
__global__ void cvt_bf16(const float* __restrict__ in, ushort_t* __restrict__ out, int n4) {
    int i = blockIdx.x * blockDim.x + threadIdx.x;
    if (i >= n4) return;
    float4 f = ((const float4*)in)[i];
    ushort4 u;
    u.x = f2bf(f.x); u.y = f2bf(f.y); u.z = f2bf(f.z); u.w = f2bf(f.w);
    ((ushort4*)out)[i] = u;
}

// ---------------- fp32 -> bf16 for the 4 weight matrices in one launch ----------
__global__ void cvt4_bf16(const float* __restrict__ w0, const float* __restrict__ w1,
                          const float* __restrict__ w2, const float* __restrict__ w3,
                          ushort_t* __restrict__ out, int n4) {
    int i = blockIdx.x * blockDim.x + threadIdx.x;
    if (i >= n4) return;
    int which = blockIdx.y;
    const float* src = which == 0 ? w0 : which == 1 ? w1 : which == 2 ? w2 : w3;
    float4 f = ((const float4*)src)[i];
    ushort4 u;
    u.x = f2bf(f.x); u.y = f2bf(f.y); u.z = f2bf(f.z); u.w = f2bf(f.w);
    ((ushort4*)(out + (size_t)which * DMODEL * DMODEL))[i] = u;
}

// ---------------- RoPE tables [S][64] ----------------
__global__ void rope_tables(float* __restrict__ cosT, float* __restrict__ sinT) {
    int i = blockIdx.x * blockDim.x + threadIdx.x; // 2048*64
    int s = i >> 6, f = i & 63;
    float inv = powf(10000.0f, -(float)(2 * f) / 128.0f);
    float ang = (float)s * inv;
    cosT[i] = cosf(ang);
    sinT[i] = sinf(ang);
}

// ---------------- RoPE in-place on Q and K ([BH][S][HD] bf16) ----------------
__global__ void rope_inplace(ushort_t* __restrict__ Q, ushort_t* __restrict__ K,
                             const float* __restrict__ cosT, const float* __restrict__ sinT) {
    long i = (long)blockIdx.x * blockDim.x + threadIdx.x; // 32*2048*64
    int f = (int)(i & 63);
    long t = i >> 6;
    int s = (int)(t & (S_LEN - 1));
    int bh = (int)(t >> 11);
    long base = ((long)bh * S_LEN + s) * HDIM;
    float c = cosT[s * 64 + f], sn = sinT[s * 64 + f];
    float a0 = bf2f(Q[base + f]), a1 = bf2f(Q[base + 64 + f]);
    Q[base + f]      = f2bf(a0 * c - a1 * sn);
    Q[base + 64 + f] = f2bf(a1 * c + a0 * sn);
    float b0 = bf2f(K[base + f]), b1 = bf2f(K[base + 64 + f]);
    K[base + f]      = f2bf(b0 * c - b1 * sn);
    K[base + 64 + f] = f2bf(b1 * c + b0 * sn);
}

// ====== gemm_qkv4: BM=128, BN=256, BK=32, 256 threads (4 waves 1x4) ======
// R9's proven single-phase body + 3 blocks/CU (48 KB LDS) + per-wave 128x64
// (fragment-reads/MFMA 0.375). With 64-B LDS rows the 16-row x 4-slot fragment
// read is inherently bank-balanced -> NO swizzle, linear staging.
// Grid 768 = 3 x 256 exactly co-resident; XCD owns 3 B-col-blocks (cpx=3).
__global__ __launch_bounds__(256) void gemm_qkv4(
    const ushort_t* __restrict__ A, const ushort_t* __restrict__ Bm,
    ushort_t* __restrict__ Cq, ushort_t* __restrict__ Ck, ushort_t* __restrict__ Cv,
    int K) {
    __shared__ __align__(16) ushort_t As[2][128 * 32];
    __shared__ __align__(16) ushort_t Bs[2][256 * 32];
    const int tid = threadIdx.x;
    const int lane = tid & 63;
    const int w = tid >> 6;                 // n-wave, 64-col slice
    const int fr = lane & 15, g = lane >> 4;
    // 768 blocks: xcd owns 3 col-blocks of 24; 32 row-blocks within.
    const int xcd = blockIdx.x & 7;
    const int local = blockIdx.x >> 3;      // 0..95
    const int brow = (local / 3) * 128;
    const int bcol = (xcd * 3 + local % 3) * 256;

    // hoisted staging bases (element units); linear dest, linear source
    const ushort_t* aSrc[2];
    const ushort_t* bSrc[4];
    int aDst[2], bDst[4];
#pragma unroll
    for (int q = 0; q < 2; q++) {
        int d = (q * 256 + tid) * 16;       // dest byte
        int row = d >> 6;                   // 64-B rows
        aSrc[q] = A + (long)(brow + row) * K + ((d & 63) >> 1);
        aDst[q] = (q * 256 + tid) * 8;
    }
#pragma unroll
    for (int q = 0; q < 4; q++) {
        int d = (q * 256 + tid) * 16;
        int row = d >> 6;
        bSrc[q] = Bm + (long)(bcol + row) * K + ((d & 63) >> 1);
        bDst[q] = (q * 256 + tid) * 8;
    }

    f32x4 acc[8][4];
#pragma unroll
    for (int m = 0; m < 8; m++)
#pragma unroll
        for (int n = 0; n < 4; n++) acc[m][n] = (f32x4){0.f, 0.f, 0.f, 0.f};

    auto stage = [&](int buf, int k0) {
#pragma unroll
        for (int q = 0; q < 2; q++) async16(aSrc[q] + k0, &As[buf][aDst[q]]);
#pragma unroll
        for (int q = 0; q < 4; q++) async16(bSrc[q] + k0, &Bs[buf][bDst[q]]);
    };
    auto rdA = [&](int buf, int m) -> bf16x8 {
        return *(const bf16x8*)&As[buf][(m * 16 + fr) * 32 + g * 8];
    };
    auto rdB = [&](int buf, int n) -> bf16x8 {
        return *(const bf16x8*)&Bs[buf][(w * 64 + n * 16 + fr) * 32 + g * 8];
    };

    const int NT = K / 32;                  // 64 tiles
    stage(0, 0);
    stage(1, 32);

    for (int kt = 0; kt < NT; ++kt) {
        const int cur = kt & 1;
        if (kt + 1 < NT) asm volatile("s_waitcnt vmcnt(6)" ::: "memory");
        else             asm volatile("s_waitcnt vmcnt(0)" ::: "memory");
        __builtin_amdgcn_sched_barrier(0);
        __builtin_amdgcn_s_barrier();
        __builtin_amdgcn_sched_barrier(0);

        bf16x8 bfv[4], af[8];
#pragma unroll
        for (int n = 0; n < 4; n++) bfv[n] = rdB(cur, n);
#pragma unroll
        for (int m = 0; m < 8; m++) af[m] = rdA(cur, m);
        __builtin_amdgcn_s_setprio(1);
#pragma unroll
        for (int m = 0; m < 8; m++)
#pragma unroll
            for (int n = 0; n < 4; n++)
                acc[m][n] = __builtin_amdgcn_mfma_f32_16x16x32_bf16(af[m], bfv[n], acc[m][n], 0, 0, 0);
        __builtin_amdgcn_s_setprio(0);

        __builtin_amdgcn_s_barrier();
        __builtin_amdgcn_sched_barrier(0);
        if (kt + 2 < NT) stage(cur, (kt + 2) * 32);
    }

    // ---- epilogue: fused [Q|K|V] scatter (block fully within one projection) ----
    const int proj = bcol >> 11;            // 0=Q, 1=K, 2=V
    const int cbase = (bcol & 2047) + w * 64;
    if (proj < 2) {
        ushort_t* dst = proj == 0 ? Cq : Ck;
#pragma unroll
        for (int n = 0; n < 4; n++) {
            int c2 = cbase + n * 16 + fr;
            int h = c2 >> 7, hd = c2 & 127;
#pragma unroll
            for (int m = 0; m < 8; m++)
#pragma unroll
                for (int r = 0; r < 4; r++) {
                    int row = brow + m * 16 + g * 4 + r;
                    int b = row >> 11, s = row & (S_LEN - 1);
                    dst[(((long)(b * NH + h) * S_LEN) + s) * HDIM + hd] = f2bf(acc[m][n][r]);
                }
        }
    } else {
#pragma unroll
        for (int n = 0; n < 4; n++) {
            int c2 = cbase + n * 16 + fr;
            int h = c2 >> 7, hd = c2 & 127;
#pragma unroll
            for (int m = 0; m < 8; m++) {
                int row0 = brow + m * 16 + g * 4;
                int b = row0 >> 11, s0 = row0 & (S_LEN - 1);
                ushort4 u;
                u.x = f2bf(acc[m][n][0]); u.y = f2bf(acc[m][n][1]);
                u.z = f2bf(acc[m][n][2]); u.w = f2bf(acc[m][n][3]);
                *(ushort4*)&Cv[(((long)(b * NH + h) * HDIM) + hd) * S_LEN + s0] = u;
            }
        }
    }
}

// ====== gemm128_o (O-proj): BM=128, BN=128, BK=64, 256 threads, 2 blocks/CU (R9) ======
__global__ __launch_bounds__(256) void gemm128_o(
    const ushort_t* __restrict__ A, const ushort_t* __restrict__ Bm,
    float* __restrict__ C0, int NB, int K) {
    __shared__ __align__(16) ushort_t As[2][128 * 64];
    __shared__ __align__(16) ushort_t Bs[2][128 * 64];
    const int tid = threadIdx.x;
    const int lane = tid & 63;
    const int w = tid >> 6;
    const int fr = lane & 15, g = lane >> 4;
    const int cpx = NB >> 3;
    const int xcd = blockIdx.x & 7;
    const int local = blockIdx.x >> 3;
    const int brow = (local / cpx) * 128;
    const int bcol = (xcd * cpx + local % cpx) * 128;

    const ushort_t* aSrc[4]; const ushort_t* bSrc[4];
    int aDst[4], bDst[4];
#pragma unroll
    for (int q = 0; q < 4; q++) {
        int d = (q * 256 + tid) * 16;
        int row = d >> 7;
        int s = d ^ ((row & 7) << 4);
        aSrc[q] = A + (long)(brow + row) * K + ((s & 127) >> 1);
        bSrc[q] = Bm + (long)(bcol + row) * K + ((s & 127) >> 1);
        aDst[q] = bDst[q] = (q * 256 + tid) * 8;
    }

    f32x4 acc[8][2];
#pragma unroll
    for (int m = 0; m < 8; m++)
#pragma unroll
        for (int n = 0; n < 2; n++) acc[m][n] = (f32x4){0.f, 0.f, 0.f, 0.f};

    auto stage = [&](int buf, int k0) {
#pragma unroll
        for (int q = 0; q < 4; q++) async16(aSrc[q] + k0, &As[buf][aDst[q]]);
#pragma unroll
        for (int q = 0; q < 4; q++) async16(bSrc[q] + k0, &Bs[buf][bDst[q]]);
    };
    auto rdA = [&](int buf, int m, int ks) -> bf16x8 {
        int row = m * 16 + fr;
        int cb = (ks * 64 + g * 16) ^ ((row & 7) << 4);
        return *(const bf16x8*)((const char*)&As[buf][0] + row * 128 + cb);
    };
    auto rdB = [&](int buf, int n, int ks) -> bf16x8 {
        int row = w * 32 + n * 16 + fr;
        int cb = (ks * 64 + g * 16) ^ ((row & 7) << 4);
        return *(const bf16x8*)((const char*)&Bs[buf][0] + row * 128 + cb);
    };

    const int NT = K / 64;
    stage(0, 0);
    stage(1, 64);

    for (int kt = 0; kt < NT; ++kt) {
        const int cur = kt & 1;
        if (kt + 1 < NT) asm volatile("s_waitcnt vmcnt(8)" ::: "memory");
        else             asm volatile("s_waitcnt vmcnt(0)" ::: "memory");
        __builtin_amdgcn_sched_barrier(0);
        __builtin_amdgcn_s_barrier();
        __builtin_amdgcn_sched_barrier(0);

        bf16x8 bfv[2][2], af[8][2];
#pragma unroll
        for (int n = 0; n < 2; n++)
#pragma unroll
            for (int ks = 0; ks < 2; ks++) bfv[n][ks] = rdB(cur, n, ks);
#pragma unroll
        for (int m = 0; m < 8; m++)
#pragma unroll
            for (int ks = 0; ks < 2; ks++) af[m][ks] = rdA(cur, m, ks);
        __builtin_amdgcn_s_setprio(1);
#pragma unroll
        for (int m = 0; m < 8; m++)
#pragma unroll
            for (int n = 0; n < 2; n++)
#pragma unroll
                for (int ks = 0; ks < 2; ks++)
                    acc[m][n] = __builtin_amdgcn_mfma_f32_16x16x32_bf16(af[m][ks], bfv[n][ks], acc[m][n], 0, 0, 0);
        __builtin_amdgcn_s_setprio(0);

        __builtin_amdgcn_s_barrier();
        __builtin_amdgcn_sched_barrier(0);
        if (kt + 2 < NT) stage(cur, (kt + 2) * 64);
    }

#pragma unroll
    for (int m = 0; m < 8; m++)
#pragma unroll
        for (int n = 0; n < 2; n++) {
            int col = bcol + w * 32 + n * 16 + fr;
#pragma unroll
            for (int r = 0; r < 4; r++) {
                int row = brow + m * 16 + g * 4 + r;
                C0[(long)row * DMODEL + col] = acc[m][n][r];
            }
        }
}

// ---------------- Flash attention v4: uniform work pairing (R9, unchanged) ----------
__global__ __launch_bounds__(256) void attn_fwd_v4(
    const ushort_t* __restrict__ Q, const ushort_t* __restrict__ K,
    const ushort_t* __restrict__ Vt, ushort_t* __restrict__ ctx) {
    __shared__ __align__(16) ushort_t Ks[2][64 * 128];
    __shared__ __align__(16) ushort_t Vs[2][128 * 64];
    __shared__ __align__(16) ushort_t Pls[4][16 * 64];

    const int tid = threadIdx.x;
    const int lane = tid & 63;
    const int w = tid >> 6;
    const int g = lane >> 4;
    const int fr = lane & 15;
    const int fk = g * 8;

    const int bid = blockIdx.x;              // 512 blocks
    const int xcd = bid & 7;
    const int t6 = bid >> 3;                 // 0..63
    const int bh = xcd + 8 * (t6 & 3);       // 4 heads per XCD
    const int p = t6 >> 2;                   // 0..15 pair index
    const int qtA = p, qtB = 31 - p;
    const int b = bh >> 4, h = bh & 15;

    const ushort_t* Qb = Q + (long)bh * S_LEN * HDIM;
    const ushort_t* Kb = K + (long)bh * S_LEN * HDIM;
    const ushort_t* Vb = Vt + (long)bh * HDIM * S_LEN;

    int koff[4], voff[4], kdst[4], vdst[4];
#pragma unroll
    for (int r = 0; r < 4; r++) {
        int ci = r * 256 + tid;
        int krow = ci >> 4, kwc = ci & 15;
        koff[r] = krow * HDIM + ((kwc ^ (krow & 7)) * 8);
        kdst[r] = ci * 8;
        int vrow = ci >> 3, vwc = ci & 7;
        voff[r] = vrow * S_LEN + ((vwc ^ (vrow & 7)) * 8);
        vdst[r] = ci * 8;
    }
    auto stage = [&](int buf, int kv0) {
        const ushort_t* Kg = Kb + (long)kv0 * HDIM;
        const ushort_t* Vg = Vb + kv0;
#pragma unroll
        for (int r = 0; r < 4; r++) async16(Kg + koff[r], &Ks[buf][kdst[r]]);
#pragma unroll
        for (int r = 0; r < 4; r++) async16(Vg + voff[r], &Vs[buf][vdst[r]]);
    };

    int qrow0 = qtA * 64 + w * 16;
    bf16x8 qf[4];
    auto loadQ = [&]() {
#pragma unroll
        for (int t = 0; t < 4; t++)
            qf[t] = *(const bf16x8*)&Qb[(long)(qrow0 + fr) * HDIM + t * 32 + fk];
    };
    loadQ();

    f32x4 o[8];
#pragma unroll
    for (int i = 0; i < 8; i++) o[i] = (f32x4){0.f, 0.f, 0.f, 0.f};
    float mrun = -1e30f, lrun = 0.f;

    const float scale = 0.08838834764831845f; // 1/sqrt(128)
    long obase = ((long)b * S_LEN) * DMODEL + (long)h * HDIM;
    auto flush = [&]() {
        float inv = 1.0f / lrun;
        long rowb = obase + (long)(qrow0 + fr) * DMODEL;
#pragma unroll
        for (int dt = 0; dt < 8; dt++) {
            ushort4 u;
            u.x = f2bf(o[dt][0] * inv); u.y = f2bf(o[dt][1] * inv);
            u.z = f2bf(o[dt][2] * inv); u.w = f2bf(o[dt][3] * inv);
            *(ushort4*)&ctx[rowb + dt * 16 + g * 4] = u;
        }
    };

    const int ntA = qtA + 1;
    const int ntot = 33; // ntA + (qtB+1) = 33 for every block

    stage(0, 0);
    __syncthreads();

    int cur = 0;
    for (int u = 0; u < ntot; ++u) {
        if (u + 1 < ntot) {
            int kvn = (u + 1 < ntA) ? (u + 1) : (u + 1 - ntA);
            stage(cur ^ 1, kvn * 64);
        }
        const int kv0 = ((u < ntA) ? u : (u - ntA)) * 64;
        if (u == ntA) { // phase switch A -> B
            flush();
            qrow0 = qtB * 64 + w * 16;
            loadQ();
#pragma unroll
            for (int i = 0; i < 8; i++) o[i] = (f32x4){0.f, 0.f, 0.f, 0.f};
            mrun = -1e30f; lrun = 0.f;
        }
        if (kv0 <= qrow0 + 15) {
            // ---- QK^T (swapped: A=K rows=kv, B=Q cols=q) ----
            f32x4 sf[4]; // [c]: kv = kv0+c*16+g*4+r, q = qrow0+fr
#pragma unroll
            for (int c = 0; c < 4; c++) sf[c] = (f32x4){0.f, 0.f, 0.f, 0.f};
            __builtin_amdgcn_s_setprio(1);
#pragma unroll
            for (int c = 0; c < 4; c++) {
                const int krow = c * 16 + fr;
#pragma unroll
                for (int tt = 0; tt < 4; tt++) {
                    bf16x8 kb = *(const bf16x8*)&Ks[cur][krow * 128 + (((tt * 4 + g) ^ (krow & 7)) * 8)];
                    sf[c] = __builtin_amdgcn_mfma_f32_16x16x32_bf16(kb, qf[tt], sf[c], 0, 0, 0);
                }
            }
            __builtin_amdgcn_s_setprio(0);
            // ---- scale + causal mask ----
            if (kv0 + 63 <= qrow0) {
#pragma unroll
                for (int c = 0; c < 4; c++)
#pragma unroll
                    for (int r = 0; r < 4; r++) sf[c][r] *= scale;
            } else {
                const int q = qrow0 + fr;
#pragma unroll
                for (int c = 0; c < 4; c++)
#pragma unroll
                    for (int r = 0; r < 4; r++) {
                        int kv = kv0 + c * 16 + g * 4 + r;
                        sf[c][r] = (kv <= q) ? sf[c][r] * scale : -1e30f;
                    }
            }
            // ---- online softmax (lane owns 16 kv of its q-row) ----
            {
                float vmax = -1e30f;
#pragma unroll
                for (int c = 0; c < 4; c++) {
                    float t0 = fmaxf(fmaxf(sf[c][0], sf[c][1]), fmaxf(sf[c][2], sf[c][3]));
                    vmax = fmaxf(vmax, t0);
                }
                vmax = fmaxf(vmax, __shfl_xor(vmax, 16));
                vmax = fmaxf(vmax, __shfl_xor(vmax, 32));
                if (!__all(vmax - mrun <= 8.f)) { // defer-max
                    float nm = fmaxf(mrun, vmax);
                    float alpha = __expf(mrun - nm);
                    mrun = nm;
                    lrun *= alpha;
#pragma unroll
                    for (int dt = 0; dt < 8; dt++) o[dt] *= alpha;
                }
                float rs = 0.f;
#pragma unroll
                for (int c = 0; c < 4; c++)
#pragma unroll
                    for (int r = 0; r < 4; r++) {
                        float pv = __expf(sf[c][r] - mrun);
                        sf[c][r] = pv;
                        rs += pv;
                    }
                rs += __shfl_xor(rs, 16);
                rs += __shfl_xor(rs, 32);
                lrun += rs;
            }
            // ---- P -> LDS [q=16][kv=64], b64-packed, XOR-swizzled ----
#pragma unroll
            for (int c = 0; c < 4; c++) {
                ushort4 u;
                u.x = f2bf(sf[c][0]); u.y = f2bf(sf[c][1]);
                u.z = f2bf(sf[c][2]); u.w = f2bf(sf[c][3]);
                *(ushort4*)&Pls[w][fr * 64 + ((c * 16 + g * 4) ^ ((fr & 7) << 3))] = u;
            }
            bf16x8 pa[2]; // B-frag: P[kv=hh*32+g*8+j][q=fr]
#pragma unroll
            for (int hh = 0; hh < 2; hh++)
                pa[hh] = *(const bf16x8*)&Pls[w][fr * 64 + ((hh * 32 + g * 8) ^ ((fr & 7) << 3))];
            // ---- PV: o = mfma(A=V^T rows=d, B=P cols=q) ----
            __builtin_amdgcn_s_setprio(1);
#pragma unroll
            for (int dt = 0; dt < 8; dt++) {
                const int vrow = dt * 16 + fr;
#pragma unroll
                for (int hh = 0; hh < 2; hh++) {
                    bf16x8 vb = *(const bf16x8*)&Vs[cur][vrow * 64 + (((hh * 4 + g) ^ (vrow & 7)) * 8)];
                    o[dt] = __builtin_amdgcn_mfma_f32_16x16x32_bf16(vb, pa[hh], o[dt], 0, 0, 0);
                }
            }
            __builtin_amdgcn_s_setprio(0);
        }
        __syncthreads();
        cur ^= 1;
    }
    flush();
}

extern "C" void kernel_launch(void* const* d_in, const int* in_sizes, int n_in,
                              void* d_out, int out_size, void* d_ws, size_t ws_size,
                              hipStream_t stream) {
    const float* hs = (const float*)d_in[0];
    const float* Wq = (const float*)d_in[1];
    const float* Wk = (const float*)d_in[2];
    const float* Wv = (const float*)d_in[3];
    const float* Wo = (const float*)d_in[4];
    float* out = (float*)d_out;

    size_t off = 0;
    char* wsb = (char*)d_ws;
    auto carve = [&](size_t bytes) { void* p = wsb + off; off += bytes; return p; };

    ushort_t* Xb   = (ushort_t*)carve((size_t)M_ROWS * DMODEL * 2);
    ushort_t* Wqb  = (ushort_t*)carve((size_t)DMODEL * DMODEL * 2); // Wq|Wk|Wv|Wo contiguous
    ushort_t* Wkb  = (ushort_t*)carve((size_t)DMODEL * DMODEL * 2);
    ushort_t* Wvb  = (ushort_t*)carve((size_t)DMODEL * DMODEL * 2);
    ushort_t* Wob  = (ushort_t*)carve((size_t)DMODEL * DMODEL * 2);
    ushort_t* Qb   = (ushort_t*)carve((size_t)BATCH * NH * S_LEN * HDIM * 2);
    ushort_t* Kb   = (ushort_t*)carve((size_t)BATCH * NH * S_LEN * HDIM * 2);
    ushort_t* Vtb  = (ushort_t*)carve((size_t)BATCH * NH * S_LEN * HDIM * 2);
    ushort_t* ctxb = (ushort_t*)carve((size_t)M_ROWS * DMODEL * 2);
    float* cosT    = (float*)carve((size_t)S_LEN * 64 * 4);
    float* sinT    = (float*)carve((size_t)S_LEN * 64 * 4);

    const int nX = M_ROWS * DMODEL;   // 8388608
    const int nW = DMODEL * DMODEL;   // 4194304

    cvt_bf16<<<(nX / 4) / 256, 256, 0, stream>>>(hs, Xb, nX / 4);
    cvt4_bf16<<<dim3((nW / 4) / 256, 4), 256, 0, stream>>>(Wq, Wk, Wv, Wo, Wqb, nW / 4);
    rope_tables<<<(S_LEN * 64) / 256, 256, 0, stream>>>(cosT, sinT);

    // Fused QKV projection: A = Xb [4096][2048], B = Wqb..Wvb as [6144][2048].
    // BM=128, BN=256 -> grid 32 x 24 = 768 blocks = 3/CU exactly co-resident.
    gemm_qkv4<<<768, 256, 0, stream>>>(Xb, Wqb, Qb, Kb, Vtb, DMODEL);

    rope_inplace<<<(BATCH * NH * S_LEN * 64) / 256, 256, 0, stream>>>(Qb, Kb, cosT, sinT);

    attn_fwd_v4<<<512, 256, 0, stream>>>(Qb, Kb, Vtb, ctxb);

    // Output projection: BM=128, BN=128 -> grid 32 x 16 = 512 blocks = 1 pair-round.
    gemm128_o<<<(M_ROWS / 128) * (DMODEL / 128), 256, 0, stream>>>(
        ctxb, Wob, out, DMODEL / 128, DMODEL);
}

// Round 12
// 339.582 us; speedup vs baseline: 1.0059x; 1.0059x over previous
//
#include <hip/hip_runtime.h>

typedef unsigned short ushort_t;
typedef __bf16 bf16x8 __attribute__((ext_vector_type(8)));
typedef float f32x4 __attribute__((ext_vector_type(4)));

#define S_LEN 2048
#define DMODEL 2048
#define NH 16
#define HDIM 128
#define BATCH 2
#define M_ROWS (BATCH * S_LEN) // 4096

__device__ __forceinline__ ushort_t f2bf(float f) {
    union { float f; unsigned u; } v; v.f = f;
    unsigned r = (v.u + 0x7fffu + ((v.u >> 16) & 1u)) >> 16;
    return (ushort_t)r;
}
__device__ __forceinline__ float bf2f(ushort_t u) {
    union { unsigned u; float f; } v; v.u = ((unsigned)u) << 16;
    return v.f;
}

__device__ __forceinline__ void async16(const void* g, void* l) {
    __builtin_amdgcn_global_load_lds(
        (const __attribute__((address_space(1))) void*)g,
        (__attribute__((address_space(3))) void*)l, 16, 0, 0);
}

// ---------------- fp32 -> bf16 (4 elems/thread) ----------------
__global__ void cvt_bf16(const float* __restrict__ in, ushort_t* __restrict__ out, int n4) {
    int i = blockIdx.x * blockDim.x + threadIdx.x;
    if (i >= n4) return;
    float4 f = ((const float4*)in)[i];
    ushort4 u;
    u.x = f2bf(f.x); u.y = f2bf(f.y); u.z = f2bf(f.z); u.w = f2bf(f.w);
    ((ushort4*)out)[i] = u;
}

// ---------------- fp32 -> bf16 for the 4 weight matrices in one launch ----------
__global__ void cvt4_bf16(const float* __restrict__ w0, const float* __restrict__ w1,
                          const float* __restrict__ w2, const float* __restrict__ w3,
                          ushort_t* __restrict__ out, int n4) {
    int i = blockIdx.x * blockDim.x + threadIdx.x;
    if (i >= n4) return;
    int which = blockIdx.y;
    const float* src = which == 0 ? w0 : which == 1 ? w1 : which == 2 ? w2 : w3;
    float4 f = ((const float4*)src)[i];
    ushort4 u;
    u.x = f2bf(f.x); u.y = f2bf(f.y); u.z = f2bf(f.z); u.w = f2bf(f.w);
    ((ushort4*)(out + (size_t)which * DMODEL * DMODEL))[i] = u;
}

// ---------------- RoPE tables [S][64] ----------------
__global__ void rope_tables(float* __restrict__ cosT, float* __restrict__ sinT) {
    int i = blockIdx.x * blockDim.x + threadIdx.x; // 2048*64
    int s = i >> 6, f = i & 63;
    float inv = powf(10000.0f, -(float)(2 * f) / 128.0f);
    float ang = (float)s * inv;
    cosT[i] = cosf(ang);
    sinT[i] = sinf(ang);
}

// ---------------- RoPE in-place on Q and K ([BH][S][HD] bf16) ----------------
__global__ void rope_inplace(ushort_t* __restrict__ Q, ushort_t* __restrict__ K,
                             const float* __restrict__ cosT, const float* __restrict__ sinT) {
    long i = (long)blockIdx.x * blockDim.x + threadIdx.x; // 32*2048*64
    int f = (int)(i & 63);
    long t = i >> 6;
    int s = (int)(t & (S_LEN - 1));
    int bh = (int)(t >> 11);
    long base = ((long)bh * S_LEN + s) * HDIM;
    float c = cosT[s * 64 + f], sn = sinT[s * 64 + f];
    float a0 = bf2f(Q[base + f]), a1 = bf2f(Q[base + 64 + f]);
    Q[base + f]      = f2bf(a0 * c - a1 * sn);
    Q[base + 64 + f] = f2bf(a1 * c + a0 * sn);
    float b0 = bf2f(K[base + f]), b1 = bf2f(K[base + 64 + f]);
    K[base + f]      = f2bf(b0 * c - b1 * sn);
    K[base + 64 + f] = f2bf(b1 * c + b0 * sn);
}

// ====== gemm128 (R9, verified 250µs config): BM=128, BN=NF*64, BK=64, 4 waves ======
// LDS = 32 + 16*NF KB -> 2 blocks/CU. Occupancy-decoupled overlap (R8/R9 lesson).
// 3-bit XOR swizzle both-sides, counted-vmcnt 2-deep staging, single-region body.
template <int EPI, int NF>
__global__ __launch_bounds__(256) void gemm128(
    const ushort_t* __restrict__ A, const ushort_t* __restrict__ Bm,
    void* __restrict__ C0, void* __restrict__ C1, void* __restrict__ C2,
    int NB, int K) {
    __shared__ __align__(16) ushort_t As[2][128 * 64];
    __shared__ __align__(16) ushort_t Bs[2][NF * 64 * 64];
    const int tid = threadIdx.x;
    const int lane = tid & 63;
    const int w = tid >> 6;                 // 0..3 = n-wave
    const int fr = lane & 15, g = lane >> 4;
    const int WN = NF * 16;
    const int BN = NF * 64;
    const int cpx = NB >> 3;
    const int xcd = blockIdx.x & 7;
    const int local = blockIdx.x >> 3;
    const int brow = (local / cpx) * 128;
    const int bcol = (xcd * cpx + local % cpx) * BN;

    int aRow[4], aK[4], bRow[2 * NF], bK[2 * NF];
#pragma unroll
    for (int q = 0; q < 4; q++) {
        int d = (q * 256 + tid) * 16;
        int row = d >> 7;
        int s = d ^ ((row & 7) << 4);
        aRow[q] = row; aK[q] = (s & 127) >> 1;
    }
#pragma unroll
    for (int q = 0; q < 2 * NF; q++) {
        int d = (q * 256 + tid) * 16;
        int row = d >> 7;
        int s = d ^ ((row & 7) << 4);
        bRow[q] = row; bK[q] = (s & 127) >> 1;
    }

    f32x4 acc[8][NF];
#pragma unroll
    for (int m = 0; m < 8; m++)
#pragma unroll
        for (int n = 0; n < NF; n++) acc[m][n] = (f32x4){0.f, 0.f, 0.f, 0.f};

    auto stage = [&](int buf, int k0) {
#pragma unroll
        for (int q = 0; q < 4; q++)
            async16(&A[(long)(brow + aRow[q]) * K + k0 + aK[q]], &As[buf][(q * 256 + tid) * 8]);
#pragma unroll
        for (int q = 0; q < 2 * NF; q++)
            async16(&Bm[(long)(bcol + bRow[q]) * K + k0 + bK[q]], &Bs[buf][(q * 256 + tid) * 8]);
    };
    auto rdA = [&](int buf, int m, int ks) -> bf16x8 {
        int row = m * 16 + fr;
        int cb = (ks * 64 + g * 16) ^ ((row & 7) << 4);
        return *(const bf16x8*)((const char*)&As[buf][0] + row * 128 + cb);
    };
    auto rdB = [&](int buf, int n, int ks) -> bf16x8 {
        int row = w * WN + n * 16 + fr;
        int cb = (ks * 64 + g * 16) ^ ((row & 7) << 4);
        return *(const bf16x8*)((const char*)&Bs[buf][0] + row * 128 + cb);
    };

    const int NT = K / 64;
    stage(0, 0);
    stage(1, 64);

    for (int kt = 0; kt < NT; ++kt) {
        const int cur = kt & 1;
        if (kt + 1 < NT) {
            if constexpr (NF == 2)      asm volatile("s_waitcnt vmcnt(8)" ::: "memory");
            else                        asm volatile("s_waitcnt vmcnt(10)" ::: "memory");
        } else {
            asm volatile("s_waitcnt vmcnt(0)" ::: "memory");
        }
        __builtin_amdgcn_sched_barrier(0);
        __builtin_amdgcn_s_barrier();
        __builtin_amdgcn_sched_barrier(0);

        bf16x8 bfv[NF][2], af[8][2];
#pragma unroll
        for (int n = 0; n < NF; n++)
#pragma unroll
            for (int ks = 0; ks < 2; ks++) bfv[n][ks] = rdB(cur, n, ks);
#pragma unroll
        for (int m = 0; m < 8; m++)
#pragma unroll
            for (int ks = 0; ks < 2; ks++) af[m][ks] = rdA(cur, m, ks);
        __builtin_amdgcn_s_setprio(1);
#pragma unroll
        for (int m = 0; m < 8; m++)
#pragma unroll
            for (int n = 0; n < NF; n++)
#pragma unroll
                for (int ks = 0; ks < 2; ks++)
                    acc[m][n] = __builtin_amdgcn_mfma_f32_16x16x32_bf16(af[m][ks], bfv[n][ks], acc[m][n], 0, 0, 0);
        __builtin_amdgcn_s_setprio(0);

        __builtin_amdgcn_s_barrier();
        __builtin_amdgcn_sched_barrier(0);
        if (kt + 2 < NT) stage(cur, (kt + 2) * 64);
    }

    if constexpr (EPI == 0) {
#pragma unroll
        for (int n = 0; n < NF; n++) {
            int c2abs = bcol + w * WN + n * 16 + fr;    // [0, 6144)
            int proj = c2abs >> 11;
            int c2 = c2abs & 2047;
            int h = c2 >> 7, hd = c2 & 127;
            if (proj < 2) {
                ushort_t* dst = (ushort_t*)(proj == 0 ? C0 : C1);
#pragma unroll
                for (int m = 0; m < 8; m++)
#pragma unroll
                    for (int r = 0; r < 4; r++) {
                        int row = brow + m * 16 + g * 4 + r;
                        int b = row >> 11, s = row & (S_LEN - 1);
                        dst[(((long)(b * NH + h) * S_LEN) + s) * HDIM + hd] = f2bf(acc[m][n][r]);
                    }
            } else {
                ushort_t* dst = (ushort_t*)C2;
#pragma unroll
                for (int m = 0; m < 8; m++) {
                    int row0 = brow + m * 16 + g * 4;
                    int b = row0 >> 11, s0 = row0 & (S_LEN - 1);
                    ushort4 u;
                    u.x = f2bf(acc[m][n][0]); u.y = f2bf(acc[m][n][1]);
                    u.z = f2bf(acc[m][n][2]); u.w = f2bf(acc[m][n][3]);
                    *(ushort4*)&dst[(((long)(b * NH + h) * HDIM) + hd) * S_LEN + s0] = u;
                }
            }
        }
    } else {
        float* dst = (float*)C0;
#pragma unroll
        for (int m = 0; m < 8; m++)
#pragma unroll
            for (int n = 0; n < NF; n++) {
                int col = bcol + w * WN + n * 16 + fr;
#pragma unroll
                for (int r = 0; r < 4; r++) {
                    int row = brow + m * 16 + g * 4 + r;
                    dst[(long)row * DMODEL + col] = acc[m][n][r];
                }
            }
    }
}

// ---------------- Flash attention v5: K in LDS, V^T direct from L2 ----------
// R9's v4 with V staging removed (Common-mistake #7: V is L2-resident — 4 heads
// per XCD = 4MB K+V). LDS 72 -> 40 KB => 4 blocks/CU (2x TLP to hide exp/shuffle
// latency chains). Softmax in base-2 (fold scale*log2e, native v_exp_f32).
__global__ __launch_bounds__(256) void attn_fwd_v5(
    const ushort_t* __restrict__ Q, const ushort_t* __restrict__ K,
    const ushort_t* __restrict__ Vt, ushort_t* __restrict__ ctx) {
    __shared__ __align__(16) ushort_t Ks[2][64 * 128];
    __shared__ __align__(16) ushort_t Pls[4][16 * 64];

    const int tid = threadIdx.x;
    const int lane = tid & 63;
    const int w = tid >> 6;
    const int g = lane >> 4;
    const int fr = lane & 15;
    const int fk = g * 8;

    const int bid = blockIdx.x;              // 512 blocks
    const int xcd = bid & 7;
    const int t6 = bid >> 3;                 // 0..63
    const int bh = xcd + 8 * (t6 & 3);       // 4 heads per XCD
    const int p = t6 >> 2;                   // 0..15 pair index
    const int qtA = p, qtB = 31 - p;
    const int b = bh >> 4, h = bh & 15;

    const ushort_t* Qb = Q + (long)bh * S_LEN * HDIM;
    const ushort_t* Kb = K + (long)bh * S_LEN * HDIM;
    const ushort_t* Vb = Vt + (long)bh * HDIM * S_LEN;

    int koff[4], kdst[4];
#pragma unroll
    for (int r = 0; r < 4; r++) {
        int ci = r * 256 + tid;
        int krow = ci >> 4, kwc = ci & 15;
        koff[r] = krow * HDIM + ((kwc ^ (krow & 7)) * 8);
        kdst[r] = ci * 8;
    }
    auto stage = [&](int buf, int kv0) {
        const ushort_t* Kg = Kb + (long)kv0 * HDIM;
#pragma unroll
        for (int r = 0; r < 4; r++) async16(Kg + koff[r], &Ks[buf][kdst[r]]);
    };

    int qrow0 = qtA * 64 + w * 16;
    bf16x8 qf[4];
    auto loadQ = [&]() {
#pragma unroll
        for (int t = 0; t < 4; t++)
            qf[t] = *(const bf16x8*)&Qb[(long)(qrow0 + fr) * HDIM + t * 32 + fk];
    };
    loadQ();

    f32x4 o[8];
#pragma unroll
    for (int i = 0; i < 8; i++) o[i] = (f32x4){0.f, 0.f, 0.f, 0.f};
    float mrun = -1e30f, lrun = 0.f;

    // base-2 softmax: S2 = S * scale * log2(e); P = exp2(S2 - m2)
    const float scale2 = 0.08838834764831845f * 1.4426950408889634f;
    long obase = ((long)b * S_LEN) * DMODEL + (long)h * HDIM;
    auto flush = [&]() {
        float inv = 1.0f / lrun;
        long rowb = obase + (long)(qrow0 + fr) * DMODEL;
#pragma unroll
        for (int dt = 0; dt < 8; dt++) {
            ushort4 u;
            u.x = f2bf(o[dt][0] * inv); u.y = f2bf(o[dt][1] * inv);
            u.z = f2bf(o[dt][2] * inv); u.w = f2bf(o[dt][3] * inv);
            *(ushort4*)&ctx[rowb + dt * 16 + g * 4] = u;
        }
    };

    const int ntA = qtA + 1;
    const int ntot = 33; // every block does exactly 33 KV-tile units

    stage(0, 0);
    __syncthreads();

    int cur = 0;
    for (int u = 0; u < ntot; ++u) {
        if (u + 1 < ntot) {
            int kvn = (u + 1 < ntA) ? (u + 1) : (u + 1 - ntA);
            stage(cur ^ 1, kvn * 64);
        }
        const int kv0 = ((u < ntA) ? u : (u - ntA)) * 64;
        if (u == ntA) { // phase switch A -> B
            flush();
            qrow0 = qtB * 64 + w * 16;
            loadQ();
#pragma unroll
            for (int i = 0; i < 8; i++) o[i] = (f32x4){0.f, 0.f, 0.f, 0.f};
            mrun = -1e30f; lrun = 0.f;
        }
        if (kv0 <= qrow0 + 15) {
            // ---- QK^T (swapped: A=K rows=kv, B=Q cols=q) ----
            f32x4 sf[4]; // [c]: kv = kv0+c*16+g*4+r, q = qrow0+fr
#pragma unroll
            for (int c = 0; c < 4; c++) sf[c] = (f32x4){0.f, 0.f, 0.f, 0.f};
            __builtin_amdgcn_s_setprio(1);
#pragma unroll
            for (int c = 0; c < 4; c++) {
                const int krow = c * 16 + fr;
#pragma unroll
                for (int tt = 0; tt < 4; tt++) {
                    bf16x8 kb = *(const bf16x8*)&Ks[cur][krow * 128 + (((tt * 4 + g) ^ (krow & 7)) * 8)];
                    sf[c] = __builtin_amdgcn_mfma_f32_16x16x32_bf16(kb, qf[tt], sf[c], 0, 0, 0);
                }
            }
            __builtin_amdgcn_s_setprio(0);
            // ---- scale (base-2) + causal mask ----
            if (kv0 + 63 <= qrow0) {
#pragma unroll
                for (int c = 0; c < 4; c++)
#pragma unroll
                    for (int r = 0; r < 4; r++) sf[c][r] *= scale2;
            } else {
                const int q = qrow0 + fr;
#pragma unroll
                for (int c = 0; c < 4; c++)
#pragma unroll
                    for (int r = 0; r < 4; r++) {
                        int kv = kv0 + c * 16 + g * 4 + r;
                        sf[c][r] = (kv <= q) ? sf[c][r] * scale2 : -1e30f;
                    }
            }
            // ---- online softmax in base-2 (lane owns 16 kv of its q-row) ----
            {
                float vmax = -1e30f;
#pragma unroll
                for (int c = 0; c < 4; c++) {
                    float t0 = fmaxf(fmaxf(sf[c][0], sf[c][1]), fmaxf(sf[c][2], sf[c][3]));
                    vmax = fmaxf(vmax, t0);
                }
                vmax = fmaxf(vmax, __shfl_xor(vmax, 16));
                vmax = fmaxf(vmax, __shfl_xor(vmax, 32));
                if (!__all(vmax - mrun <= 11.5f)) { // defer-max (8 nats = 11.54 bits)
                    float nm = fmaxf(mrun, vmax);
                    float alpha = exp2f(mrun - nm);
                    mrun = nm;
                    lrun *= alpha;
#pragma unroll
                    for (int dt = 0; dt < 8; dt++) o[dt] *= alpha;
                }
                float rs = 0.f;
#pragma unroll
                for (int c = 0; c < 4; c++)
#pragma unroll
                    for (int r = 0; r < 4; r++) {
                        float pv = exp2f(sf[c][r] - mrun);
                        sf[c][r] = pv;
                        rs += pv;
                    }
                rs += __shfl_xor(rs, 16);
                rs += __shfl_xor(rs, 32);
                lrun += rs;
            }
            // ---- P -> LDS [q=16][kv=64], b64-packed, XOR-swizzled ----
#pragma unroll
            for (int c = 0; c < 4; c++) {
                ushort4 u;
                u.x = f2bf(sf[c][0]); u.y = f2bf(sf[c][1]);
                u.z = f2bf(sf[c][2]); u.w = f2bf(sf[c][3]);
                *(ushort4*)&Pls[w][fr * 64 + ((c * 16 + g * 4) ^ ((fr & 7) << 3))] = u;
            }
            bf16x8 pa[2]; // B-frag: P[kv=hh*32+g*8+j][q=fr]
#pragma unroll
            for (int hh = 0; hh < 2; hh++)
                pa[hh] = *(const bf16x8*)&Pls[w][fr * 64 + ((hh * 32 + g * 8) ^ ((fr & 7) << 3))];
            // ---- PV: o = mfma(A=V^T rows=d from GLOBAL (L2-hit), B=P cols=q) ----
            __builtin_amdgcn_s_setprio(1);
#pragma unroll
            for (int dt = 0; dt < 8; dt++) {
                const long vrow = (long)(dt * 16 + fr) * S_LEN + kv0;
#pragma unroll
                for (int hh = 0; hh < 2; hh++) {
                    bf16x8 vb = *(const bf16x8*)&Vb[vrow + hh * 32 + g * 8];
                    o[dt] = __builtin_amdgcn_mfma_f32_16x16x32_bf16(vb, pa[hh], o[dt], 0, 0, 0);
                }
            }
            __builtin_amdgcn_s_setprio(0);
        }
        __syncthreads();
        cur ^= 1;
    }
    flush();
}

extern "C" void kernel_launch(void* const* d_in, const int* in_sizes, int n_in,
                              void* d_out, int out_size, void* d_ws, size_t ws_size,
                              hipStream_t stream) {
    const float* hs = (const float*)d_in[0];
    const float* Wq = (const float*)d_in[1];
    const float* Wk = (const float*)d_in[2];
    const float* Wv = (const float*)d_in[3];
    const float* Wo = (const float*)d_in[4];
    float* out = (float*)d_out;

    size_t off = 0;
    char* wsb = (char*)d_ws;
    auto carve = [&](size_t bytes) { void* p = wsb + off; off += bytes; return p; };

    ushort_t* Xb   = (ushort_t*)carve((size_t)M_ROWS * DMODEL * 2);
    ushort_t* Wqb  = (ushort_t*)carve((size_t)DMODEL * DMODEL * 2); // Wq|Wk|Wv|Wo contiguous
    ushort_t* Wkb  = (ushort_t*)carve((size_t)DMODEL * DMODEL * 2);
    ushort_t* Wvb  = (ushort_t*)carve((size_t)DMODEL * DMODEL * 2);
    ushort_t* Wob  = (ushort_t*)carve((size_t)DMODEL * DMODEL * 2);
    ushort_t* Qb   = (ushort_t*)carve((size_t)BATCH * NH * S_LEN * HDIM * 2);
    ushort_t* Kb   = (ushort_t*)carve((size_t)BATCH * NH * S_LEN * HDIM * 2);
    ushort_t* Vtb  = (ushort_t*)carve((size_t)BATCH * NH * S_LEN * HDIM * 2);
    ushort_t* ctxb = (ushort_t*)carve((size_t)M_ROWS * DMODEL * 2);
    float* cosT    = (float*)carve((size_t)S_LEN * 64 * 4);
    float* sinT    = (float*)carve((size_t)S_LEN * 64 * 4);

    const int nX = M_ROWS * DMODEL;   // 8388608
    const int nW = DMODEL * DMODEL;   // 4194304

    cvt_bf16<<<(nX / 4) / 256, 256, 0, stream>>>(hs, Xb, nX / 4);
    cvt4_bf16<<<dim3((nW / 4) / 256, 4), 256, 0, stream>>>(Wq, Wk, Wv, Wo, Wqb, nW / 4);
    rope_tables<<<(S_LEN * 64) / 256, 256, 0, stream>>>(cosT, sinT);

    // Fused QKV projection: A = Xb [4096][2048], B = Wqb..Wvb as [6144][2048].
    // BM=128, BN=192 -> grid 32 x 32 = 1024 blocks; 2 blocks/CU -> 2 pair-rounds.
    gemm128<0, 3><<<(M_ROWS / 128) * (3 * DMODEL / 192), 256, 0, stream>>>(
        Xb, Wqb, Qb, Kb, Vtb, 3 * DMODEL / 192, DMODEL);

    rope_inplace<<<(BATCH * NH * S_LEN * 64) / 256, 256, 0, stream>>>(Qb, Kb, cosT, sinT);

    attn_fwd_v5<<<512, 256, 0, stream>>>(Qb, Kb, Vtb, ctxb);

    // Output projection: BM=128, BN=128 -> grid 32 x 16 = 512 blocks = 1 pair-round.
    gemm128<2, 2><<<(M_ROWS / 128) * (DMODEL / 128), 256, 0, stream>>>(
        ctxb, Wob, out, nullptr, nullptr, DMODEL / 128, DMODEL);
}

// Round 13
// 257.772 us; speedup vs baseline: 1.3251x; 1.3174x over previous
//
#include <hip/hip_runtime.h>

typedef unsigned short ushort_t;
typedef __bf16 bf16x8 __attribute__((ext_vector_type(8)));
typedef float f32x4 __attribute__((ext_vector_type(4)));

#define S_LEN 2048
#define DMODEL 2048
#define NH 16
#define HDIM 128
#define BATCH 2
#define M_ROWS (BATCH * S_LEN) // 4096

__device__ __forceinline__ ushort_t f2bf(float f) {
    union { float f; unsigned u; } v; v.f = f;
    unsigned r = (v.u + 0x7fffu + ((v.u >> 16) & 1u)) >> 16;
    return (ushort_t)r;
}
__device__ __forceinline__ float bf2f(ushort_t u) {
    union { unsigned u; float f; } v; v.u = ((unsigned)u) << 16;
    return v.f;
}

__device__ __forceinline__ void async16(const void* g, void* l) {
    __builtin_amdgcn_global_load_lds(
        (const __attribute__((address_space(1))) void*)g,
        (__attribute__((address_space(3))) void*)l, 16, 0, 0);
}

// ---------------- fp32 -> bf16 (4 elems/thread) ----------------
__global__ void cvt_bf16(const float* __restrict__ in, ushort_t* __restrict__ out, int n4) {
    int i = blockIdx.x * blockDim.x + threadIdx.x;
    if (i >= n4) return;
    float4 f = ((const float4*)in)[i];
    ushort4 u;
    u.x = f2bf(f.x); u.y = f2bf(f.y); u.z = f2bf(f.z); u.w = f2bf(f.w);
    ((ushort4*)out)[i] = u;
}

// ---------------- fp32 -> bf16 for the 4 weight matrices in one launch ----------
__global__ void cvt4_bf16(const float* __restrict__ w0, const float* __restrict__ w1,
                          const float* __restrict__ w2, const float* __restrict__ w3,
                          ushort_t* __restrict__ out, int n4) {
    int i = blockIdx.x * blockDim.x + threadIdx.x;
    if (i >= n4) return;
    int which = blockIdx.y;
    const float* src = which == 0 ? w0 : which == 1 ? w1 : which == 2 ? w2 : w3;
    float4 f = ((const float4*)src)[i];
    ushort4 u;
    u.x = f2bf(f.x); u.y = f2bf(f.y); u.z = f2bf(f.z); u.w = f2bf(f.w);
    ((ushort4*)(out + (size_t)which * DMODEL * DMODEL))[i] = u;
}

// ---------------- RoPE tables [S][64] ----------------
__global__ void rope_tables(float* __restrict__ cosT, float* __restrict__ sinT) {
    int i = blockIdx.x * blockDim.x + threadIdx.x; // 2048*64
    int s = i >> 6, f = i & 63;
    float inv = powf(10000.0f, -(float)(2 * f) / 128.0f);
    float ang = (float)s * inv;
    cosT[i] = cosf(ang);
    sinT[i] = sinf(ang);
}

// ---------------- RoPE in-place on Q and K ([BH][S][HD] bf16) ----------------
__global__ void rope_inplace(ushort_t* __restrict__ Q, ushort_t* __restrict__ K,
                             const float* __restrict__ cosT, const float* __restrict__ sinT) {
    long i = (long)blockIdx.x * blockDim.x + threadIdx.x; // 32*2048*64
    int f = (int)(i & 63);
    long t = i >> 6;
    int s = (int)(t & (S_LEN - 1));
    int bh = (int)(t >> 11);
    long base = ((long)bh * S_LEN + s) * HDIM;
    float c = cosT[s * 64 + f], sn = sinT[s * 64 + f];
    float a0 = bf2f(Q[base + f]), a1 = bf2f(Q[base + 64 + f]);
    Q[base + f]      = f2bf(a0 * c - a1 * sn);
    Q[base + 64 + f] = f2bf(a1 * c + a0 * sn);
    float b0 = bf2f(K[base + f]), b1 = bf2f(K[base + 64 + f]);
    K[base + f]      = f2bf(b0 * c - b1 * sn);
    K[base + 64 + f] = f2bf(b1 * c + b0 * sn);
}

// ====== gemm128 (R9, verified): BM=128, BN=NF*64, BK=64, 4 waves, 2 blocks/CU ======
template <int EPI, int NF>
__global__ __launch_bounds__(256) void gemm128(
    const ushort_t* __restrict__ A, const ushort_t* __restrict__ Bm,
    void* __restrict__ C0, void* __restrict__ C1, void* __restrict__ C2,
    int NB, int K) {
    __shared__ __align__(16) ushort_t As[2][128 * 64];
    __shared__ __align__(16) ushort_t Bs[2][NF * 64 * 64];
    const int tid = threadIdx.x;
    const int lane = tid & 63;
    const int w = tid >> 6;                 // 0..3 = n-wave
    const int fr = lane & 15, g = lane >> 4;
    const int WN = NF * 16;
    const int BN = NF * 64;
    const int cpx = NB >> 3;
    const int xcd = blockIdx.x & 7;
    const int local = blockIdx.x >> 3;
    const int brow = (local / cpx) * 128;
    const int bcol = (xcd * cpx + local % cpx) * BN;

    int aRow[4], aK[4], bRow[2 * NF], bK[2 * NF];
#pragma unroll
    for (int q = 0; q < 4; q++) {
        int d = (q * 256 + tid) * 16;
        int row = d >> 7;
        int s = d ^ ((row & 7) << 4);
        aRow[q] = row; aK[q] = (s & 127) >> 1;
    }
#pragma unroll
    for (int q = 0; q < 2 * NF; q++) {
        int d = (q * 256 + tid) * 16;
        int row = d >> 7;
        int s = d ^ ((row & 7) << 4);
        bRow[q] = row; bK[q] = (s & 127) >> 1;
    }

    f32x4 acc[8][NF];
#pragma unroll
    for (int m = 0; m < 8; m++)
#pragma unroll
        for (int n = 0; n < NF; n++) acc[m][n] = (f32x4){0.f, 0.f, 0.f, 0.f};

    auto stage = [&](int buf, int k0) {
#pragma unroll
        for (int q = 0; q < 4; q++)
            async16(&A[(long)(brow + aRow[q]) * K + k0 + aK[q]], &As[buf][(q * 256 + tid) * 8]);
#pragma unroll
        for (int q = 0; q < 2 * NF; q++)
            async16(&Bm[(long)(bcol + bRow[q]) * K + k0 + bK[q]], &Bs[buf][(q * 256 + tid) * 8]);
    };
    auto rdA = [&](int buf, int m, int ks) -> bf16x8 {
        int row = m * 16 + fr;
        int cb = (ks * 64 + g * 16) ^ ((row & 7) << 4);
        return *(const bf16x8*)((const char*)&As[buf][0] + row * 128 + cb);
    };
    auto rdB = [&](int buf, int n, int ks) -> bf16x8 {
        int row = w * WN + n * 16 + fr;
        int cb = (ks * 64 + g * 16) ^ ((row & 7) << 4);
        return *(const bf16x8*)((const char*)&Bs[buf][0] + row * 128 + cb);
    };

    const int NT = K / 64;
    stage(0, 0);
    stage(1, 64);

    for (int kt = 0; kt < NT; ++kt) {
        const int cur = kt & 1;
        if (kt + 1 < NT) {
            if constexpr (NF == 2)      asm volatile("s_waitcnt vmcnt(8)" ::: "memory");
            else                        asm volatile("s_waitcnt vmcnt(10)" ::: "memory");
        } else {
            asm volatile("s_waitcnt vmcnt(0)" ::: "memory");
        }
        __builtin_amdgcn_sched_barrier(0);
        __builtin_amdgcn_s_barrier();
        __builtin_amdgcn_sched_barrier(0);

        bf16x8 bfv[NF][2], af[8][2];
#pragma unroll
        for (int n = 0; n < NF; n++)
#pragma unroll
            for (int ks = 0; ks < 2; ks++) bfv[n][ks] = rdB(cur, n, ks);
#pragma unroll
        for (int m = 0; m < 8; m++)
#pragma unroll
            for (int ks = 0; ks < 2; ks++) af[m][ks] = rdA(cur, m, ks);
        __builtin_amdgcn_s_setprio(1);
#pragma unroll
        for (int m = 0; m < 8; m++)
#pragma unroll
            for (int n = 0; n < NF; n++)
#pragma unroll
                for (int ks = 0; ks < 2; ks++)
                    acc[m][n] = __builtin_amdgcn_mfma_f32_16x16x32_bf16(af[m][ks], bfv[n][ks], acc[m][n], 0, 0, 0);
        __builtin_amdgcn_s_setprio(0);

        __builtin_amdgcn_s_barrier();
        __builtin_amdgcn_sched_barrier(0);
        if (kt + 2 < NT) stage(cur, (kt + 2) * 64);
    }

    if constexpr (EPI == 0) {
#pragma unroll
        for (int n = 0; n < NF; n++) {
            int c2abs = bcol + w * WN + n * 16 + fr;    // [0, 6144)
            int proj = c2abs >> 11;
            int c2 = c2abs & 2047;
            int h = c2 >> 7, hd = c2 & 127;
            if (proj < 2) {
                ushort_t* dst = (ushort_t*)(proj == 0 ? C0 : C1);
#pragma unroll
                for (int m = 0; m < 8; m++)
#pragma unroll
                    for (int r = 0; r < 4; r++) {
                        int row = brow + m * 16 + g * 4 + r;
                        int b = row >> 11, s = row & (S_LEN - 1);
                        dst[(((long)(b * NH + h) * S_LEN) + s) * HDIM + hd] = f2bf(acc[m][n][r]);
                    }
            } else {
                ushort_t* dst = (ushort_t*)C2;
#pragma unroll
                for (int m = 0; m < 8; m++) {
                    int row0 = brow + m * 16 + g * 4;
                    int b = row0 >> 11, s0 = row0 & (S_LEN - 1);
                    ushort4 u;
                    u.x = f2bf(acc[m][n][0]); u.y = f2bf(acc[m][n][1]);
                    u.z = f2bf(acc[m][n][2]); u.w = f2bf(acc[m][n][3]);
                    *(ushort4*)&dst[(((long)(b * NH + h) * HDIM) + hd) * S_LEN + s0] = u;
                }
            }
        }
    } else {
        float* dst = (float*)C0;
#pragma unroll
        for (int m = 0; m < 8; m++)
#pragma unroll
            for (int n = 0; n < NF; n++) {
                int col = bcol + w * WN + n * 16 + fr;
#pragma unroll
                for (int r = 0; r < 4; r++) {
                    int row = brow + m * 16 + g * 4 + r;
                    dst[(long)row * DMODEL + col] = acc[m][n][r];
                }
            }
    }
}

// ---------------- Flash attention v4b: R9 structure + base-2 softmax ----------
__global__ __launch_bounds__(256) void attn_fwd_v4(
    const ushort_t* __restrict__ Q, const ushort_t* __restrict__ K,
    const ushort_t* __restrict__ Vt, ushort_t* __restrict__ ctx) {
    __shared__ __align__(16) ushort_t Ks[2][64 * 128];
    __shared__ __align__(16) ushort_t Vs[2][128 * 64];
    __shared__ __align__(16) ushort_t Pls[4][16 * 64];

    const int tid = threadIdx.x;
    const int lane = tid & 63;
    const int w = tid >> 6;
    const int g = lane >> 4;
    const int fr = lane & 15;
    const int fk = g * 8;

    const int bid = blockIdx.x;              // 512 blocks
    const int xcd = bid & 7;
    const int t6 = bid >> 3;                 // 0..63
    const int bh = xcd + 8 * (t6 & 3);       // 4 heads per XCD
    const int p = t6 >> 2;                   // 0..15 pair index
    const int qtA = p, qtB = 31 - p;
    const int b = bh >> 4, h = bh & 15;

    const ushort_t* Qb = Q + (long)bh * S_LEN * HDIM;
    const ushort_t* Kb = K + (long)bh * S_LEN * HDIM;
    const ushort_t* Vb = Vt + (long)bh * HDIM * S_LEN;

    int koff[4], voff[4], kdst[4], vdst[4];
#pragma unroll
    for (int r = 0; r < 4; r++) {
        int ci = r * 256 + tid;
        int krow = ci >> 4, kwc = ci & 15;
        koff[r] = krow * HDIM + ((kwc ^ (krow & 7)) * 8);
        kdst[r] = ci * 8;
        int vrow = ci >> 3, vwc = ci & 7;
        voff[r] = vrow * S_LEN + ((vwc ^ (vrow & 7)) * 8);
        vdst[r] = ci * 8;
    }
    auto stage = [&](int buf, int kv0) {
        const ushort_t* Kg = Kb + (long)kv0 * HDIM;
        const ushort_t* Vg = Vb + kv0;
#pragma unroll
        for (int r = 0; r < 4; r++) async16(Kg + koff[r], &Ks[buf][kdst[r]]);
#pragma unroll
        for (int r = 0; r < 4; r++) async16(Vg + voff[r], &Vs[buf][vdst[r]]);
    };

    int qrow0 = qtA * 64 + w * 16;
    bf16x8 qf[4];
    auto loadQ = [&]() {
#pragma unroll
        for (int t = 0; t < 4; t++)
            qf[t] = *(const bf16x8*)&Qb[(long)(qrow0 + fr) * HDIM + t * 32 + fk];
    };
    loadQ();

    f32x4 o[8];
#pragma unroll
    for (int i = 0; i < 8; i++) o[i] = (f32x4){0.f, 0.f, 0.f, 0.f};
    float mrun = -1e30f, lrun = 0.f;

    // base-2 softmax: S2 = S * scale * log2(e); P = exp2(S2 - m2)
    const float scale2 = 0.08838834764831845f * 1.4426950408889634f;
    long obase = ((long)b * S_LEN) * DMODEL + (long)h * HDIM;
    auto flush = [&]() {
        float inv = 1.0f / lrun;
        long rowb = obase + (long)(qrow0 + fr) * DMODEL;
#pragma unroll
        for (int dt = 0; dt < 8; dt++) {
            ushort4 u;
            u.x = f2bf(o[dt][0] * inv); u.y = f2bf(o[dt][1] * inv);
            u.z = f2bf(o[dt][2] * inv); u.w = f2bf(o[dt][3] * inv);
            *(ushort4*)&ctx[rowb + dt * 16 + g * 4] = u;
        }
    };

    const int ntA = qtA + 1;
    const int ntot = 33; // ntA + (qtB+1) = 33 for every block

    stage(0, 0);
    __syncthreads();

    int cur = 0;
    for (int u = 0; u < ntot; ++u) {
        if (u + 1 < ntot) {
            int kvn = (u + 1 < ntA) ? (u + 1) : (u + 1 - ntA);
            stage(cur ^ 1, kvn * 64);
        }
        const int kv0 = ((u < ntA) ? u : (u - ntA)) * 64;
        if (u == ntA) { // phase switch A -> B
            flush();
            qrow0 = qtB * 64 + w * 16;
            loadQ();
#pragma unroll
            for (int i = 0; i < 8; i++) o[i] = (f32x4){0.f, 0.f, 0.f, 0.f};
            mrun = -1e30f; lrun = 0.f;
        }
        if (kv0 <= qrow0 + 15) {
            // ---- QK^T (swapped: A=K rows=kv, B=Q cols=q) ----
            f32x4 sf[4]; // [c]: kv = kv0+c*16+g*4+r, q = qrow0+fr
#pragma unroll
            for (int c = 0; c < 4; c++) sf[c] = (f32x4){0.f, 0.f, 0.f, 0.f};
            __builtin_amdgcn_s_setprio(1);
#pragma unroll
            for (int c = 0; c < 4; c++) {
                const int krow = c * 16 + fr;
#pragma unroll
                for (int tt = 0; tt < 4; tt++) {
                    bf16x8 kb = *(const bf16x8*)&Ks[cur][krow * 128 + (((tt * 4 + g) ^ (krow & 7)) * 8)];
                    sf[c] = __builtin_amdgcn_mfma_f32_16x16x32_bf16(kb, qf[tt], sf[c], 0, 0, 0);
                }
            }
            __builtin_amdgcn_s_setprio(0);
            // ---- scale (base-2) + causal mask ----
            if (kv0 + 63 <= qrow0) {
#pragma unroll
                for (int c = 0; c < 4; c++)
#pragma unroll
                    for (int r = 0; r < 4; r++) sf[c][r] *= scale2;
            } else {
                const int q = qrow0 + fr;
#pragma unroll
                for (int c = 0; c < 4; c++)
#pragma unroll
                    for (int r = 0; r < 4; r++) {
                        int kv = kv0 + c * 16 + g * 4 + r;
                        sf[c][r] = (kv <= q) ? sf[c][r] * scale2 : -1e30f;
                    }
            }
            // ---- online softmax in base-2 (lane owns 16 kv of its q-row) ----
            {
                float vmax = -1e30f;
#pragma unroll
                for (int c = 0; c < 4; c++) {
                    float t0 = fmaxf(fmaxf(sf[c][0], sf[c][1]), fmaxf(sf[c][2], sf[c][3]));
                    vmax = fmaxf(vmax, t0);
                }
                vmax = fmaxf(vmax, __shfl_xor(vmax, 16));
                vmax = fmaxf(vmax, __shfl_xor(vmax, 32));
                if (!__all(vmax - mrun <= 11.5f)) { // defer-max (11.5 bits ~ 8 nats)
                    float nm = fmaxf(mrun, vmax);
                    float alpha = exp2f(mrun - nm);
                    mrun = nm;
                    lrun *= alpha;
#pragma unroll
                    for (int dt = 0; dt < 8; dt++) o[dt] *= alpha;
                }
                float rs = 0.f;
#pragma unroll
                for (int c = 0; c < 4; c++)
#pragma unroll
                    for (int r = 0; r < 4; r++) {
                        float pv = exp2f(sf[c][r] - mrun);
                        sf[c][r] = pv;
                        rs += pv;
                    }
                rs += __shfl_xor(rs, 16);
                rs += __shfl_xor(rs, 32);
                lrun += rs;
            }
            // ---- P -> LDS [q=16][kv=64], b64-packed, XOR-swizzled ----
#pragma unroll
            for (int c = 0; c < 4; c++) {
                ushort4 u;
                u.x = f2bf(sf[c][0]); u.y = f2bf(sf[c][1]);
                u.z = f2bf(sf[c][2]); u.w = f2bf(sf[c][3]);
                *(ushort4*)&Pls[w][fr * 64 + ((c * 16 + g * 4) ^ ((fr & 7) << 3))] = u;
            }
            bf16x8 pa[2]; // B-frag: P[kv=hh*32+g*8+j][q=fr]
#pragma unroll
            for (int hh = 0; hh < 2; hh++)
                pa[hh] = *(const bf16x8*)&Pls[w][fr * 64 + ((hh * 32 + g * 8) ^ ((fr & 7) << 3))];
            // ---- PV: o = mfma(A=V^T rows=d, B=P cols=q) ----
            __builtin_amdgcn_s_setprio(1);
#pragma unroll
            for (int dt = 0; dt < 8; dt++) {
                const int vrow = dt * 16 + fr;
#pragma unroll
                for (int hh = 0; hh < 2; hh++) {
                    bf16x8 vb = *(const bf16x8*)&Vs[cur][vrow * 64 + (((hh * 4 + g) ^ (vrow & 7)) * 8)];
                    o[dt] = __builtin_amdgcn_mfma_f32_16x16x32_bf16(vb, pa[hh], o[dt], 0, 0, 0);
                }
            }
            __builtin_amdgcn_s_setprio(0);
        }
        __syncthreads();
        cur ^= 1;
    }
    flush();
}

extern "C" void kernel_launch(void* const* d_in, const int* in_sizes, int n_in,
                              void* d_out, int out_size, void* d_ws, size_t ws_size,
                              hipStream_t stream) {
    const float* hs = (const float*)d_in[0];
    const float* Wq = (const float*)d_in[1];
    const float* Wk = (const float*)d_in[2];
    const float* Wv = (const float*)d_in[3];
    const float* Wo = (const float*)d_in[4];
    float* out = (float*)d_out;

    size_t off = 0;
    char* wsb = (char*)d_ws;
    auto carve = [&](size_t bytes) { void* p = wsb + off; off += bytes; return p; };

    ushort_t* Xb   = (ushort_t*)carve((size_t)M_ROWS * DMODEL * 2);
    ushort_t* Wqb  = (ushort_t*)carve((size_t)DMODEL * DMODEL * 2); // Wq|Wk|Wv|Wo contiguous
    ushort_t* Wkb  = (ushort_t*)carve((size_t)DMODEL * DMODEL * 2);
    ushort_t* Wvb  = (ushort_t*)carve((size_t)DMODEL * DMODEL * 2);
    ushort_t* Wob  = (ushort_t*)carve((size_t)DMODEL * DMODEL * 2);
    ushort_t* Qb   = (ushort_t*)carve((size_t)BATCH * NH * S_LEN * HDIM * 2);
    ushort_t* Kb   = (ushort_t*)carve((size_t)BATCH * NH * S_LEN * HDIM * 2);
    ushort_t* Vtb  = (ushort_t*)carve((size_t)BATCH * NH * S_LEN * HDIM * 2);
    ushort_t* ctxb = (ushort_t*)carve((size_t)M_ROWS * DMODEL * 2);
    float* cosT    = (float*)carve((size_t)S_LEN * 64 * 4);
    float* sinT    = (float*)carve((size_t)S_LEN * 64 * 4);

    const int nX = M_ROWS * DMODEL;   // 8388608
    const int nW = DMODEL * DMODEL;   // 4194304

    cvt_bf16<<<(nX / 4) / 256, 256, 0, stream>>>(hs, Xb, nX / 4);
    cvt4_bf16<<<dim3((nW / 4) / 256, 4), 256, 0, stream>>>(Wq, Wk, Wv, Wo, Wqb, nW / 4);
    rope_tables<<<(S_LEN * 64) / 256, 256, 0, stream>>>(cosT, sinT);

    // Fused QKV projection: A = Xb [4096][2048], B = Wqb..Wvb as [6144][2048].
    // BM=128, BN=192 -> grid 32 x 32 = 1024 blocks; 2 blocks/CU -> 2 pair-rounds.
    gemm128<0, 3><<<(M_ROWS / 128) * (3 * DMODEL / 192), 256, 0, stream>>>(
        Xb, Wqb, Qb, Kb, Vtb, 3 * DMODEL / 192, DMODEL);

    rope_inplace<<<(BATCH * NH * S_LEN * 64) / 256, 256, 0, stream>>>(Qb, Kb, cosT, sinT);

    attn_fwd_v4<<<512, 256, 0, stream>>>(Qb, Kb, Vtb, ctxb);

    // Output projection: BM=128, BN=128 -> grid 32 x 16 = 512 blocks = 1 pair-round.
    gemm128<2, 2><<<(M_ROWS / 128) * (DMODEL / 128), 256, 0, stream>>>(
        ctxb, Wob, out, nullptr, nullptr, DMODEL / 128, DMODEL);
}